// Round 8
// baseline (52.965 us; speedup 1.0000x reference)
//
#include <hip/hip_runtime.h>
#include <cstdint>
#include <cstddef>

#define ROWS 16384
#define COLS 1024

// rotl via single v_alignbit_b32: alignbit(x,x,32-r) = (x>>(32-r))|(x<<r)
__device__ __forceinline__ uint32_t rotl32(uint32_t x, int r) {
    return __builtin_amdgcn_alignbit(x, x, 32 - r);
}

// Four Threefry-2x32 states in lockstep (ILP within the loop body).
struct TF4 { uint32_t a0,a1,b0,b1,c0,c1,d0,d1; };

__device__ __forceinline__ void tf_round4(TF4& s, int r) {
    s.a0 += s.a1; s.b0 += s.b1; s.c0 += s.c1; s.d0 += s.d1;
    s.a1 = rotl32(s.a1, r) ^ s.a0;
    s.b1 = rotl32(s.b1, r) ^ s.b0;
    s.c1 = rotl32(s.c1, r) ^ s.c0;
    s.d1 = rotl32(s.d1, r) ^ s.d0;
}

__device__ __forceinline__ void inj4(TF4& s, uint32_t k0, uint32_t k1) {
    s.a0 += k0; s.b0 += k0; s.c0 += k0; s.d0 += k0;
    s.a1 += k1; s.b1 += k1; s.c1 += k1; s.d1 += k1;
}

__device__ __forceinline__ void inj4_x1(TF4& s, uint32_t k1) {  // x0 += 0
    s.a1 += k1; s.b1 += k1; s.c1 += k1; s.d1 += k1;
}

// Threefry-2x32-20, key (0,42), counters (0, i..i+3), bits = o0 ^ o1.
__device__ __forceinline__ uint4 threefry_bits4(uint32_t i) {
    const uint32_t ks1 = 42u;
    const uint32_t ks2 = 0x1BD11BF0u;   // 0x1BD11BDA ^ 0 ^ 42

    TF4 s;
    s.a1 = i + 42u;  s.a0 = s.a1;       // x0 = 0 + x1 after round-1 add
    s.b1 = i + 43u;  s.b0 = s.b1;
    s.c1 = i + 44u;  s.c0 = s.c1;
    s.d1 = i + 45u;  s.d0 = s.d1;
    s.a1 = rotl32(s.a1, 13) ^ s.a0;     // round-1 tail
    s.b1 = rotl32(s.b1, 13) ^ s.b0;
    s.c1 = rotl32(s.c1, 13) ^ s.c0;
    s.d1 = rotl32(s.d1, 13) ^ s.d0;
    tf_round4(s, 15); tf_round4(s, 26); tf_round4(s, 6);
    inj4(s, ks1, ks2 + 1u);
    tf_round4(s, 17); tf_round4(s, 29); tf_round4(s, 16); tf_round4(s, 24);
    inj4(s, ks2, 2u);                   // ks0 == 0
    tf_round4(s, 13); tf_round4(s, 15); tf_round4(s, 26); tf_round4(s, 6);
    inj4_x1(s, ks1 + 3u);               // x0 += 0
    tf_round4(s, 17); tf_round4(s, 29); tf_round4(s, 16); tf_round4(s, 24);
    inj4(s, ks1, ks2 + 4u);
    tf_round4(s, 13); tf_round4(s, 15); tf_round4(s, 26); tf_round4(s, 6);
    inj4(s, ks2, 5u);                   // ks0 == 0

    return make_uint4(s.a0 ^ s.a1, s.b0 ^ s.b1, s.c0 ^ s.c1, s.d0 ^ s.d1);
}

// Rare tail (w >= 5 i.e. L <= -7.2134752, ~0.33%/lane): Giles upper branch,
// coefficients pre-scaled by 1.1*sqrt(2). Takes L = log2(1 - v^2).
__device__ __noinline__ float noise_tail(float L) {
    float w = -0.69314718f * L;
    float s = __builtin_amdgcn_sqrtf(w) - 3.0f;
    float q = -3.1146030e-04f;
    q = fmaf(q, s, 1.5704224e-04f);
    q = fmaf(q, s, 2.0990855e-03f);
    q = fmaf(q, s, -5.7144932e-03f);
    q = fmaf(q, s, 8.9285939e-03f);
    q = fmaf(q, s, -1.1857797e-02f);
    q = fmaf(q, s, 1.4683435e-02f);
    q = fmaf(q, s, 1.5582439e+00f);
    q = fmaf(q, s, 4.4070777e+00f);
    return q;
}

// 4 elements, stage-interleaved. v = fma(cvt(bits>>9), 2^-22, minval) is
// bit-identical to JAX's bitcast path. Central poly: Giles coeffs pre-scaled
// by 1.1*sqrt2, re-centered directly in L = log2(1-v^2) (the former
// y = L + 2.5/ln2 shift is folded into the coefficients; continuity at the
// branch point verified: q(-7.2134752) = 3.23704 = old p(-3.6067)).
__device__ __forceinline__ float4 noise4(uint32_t idx0) {
    uint4 b = threefry_bits4(idx0);

    float f0 = (float)(b.x >> 9);
    float f1 = (float)(b.y >> 9);
    float f2 = (float)(b.z >> 9);
    float f3 = (float)(b.w >> 9);

    const float S = 2.3841858e-07f;      // 2^-22
    const float M = -0.99999994f;
    float v0 = fmaf(f0, S, M), v1 = fmaf(f1, S, M),
          v2 = fmaf(f2, S, M), v3 = fmaf(f3, S, M);

    float t0 = fmaf(-v0, v0, 1.0f), t1 = fmaf(-v1, v1, 1.0f),
          t2 = fmaf(-v2, v2, 1.0f), t3 = fmaf(-v3, v3, 1.0f);

    float L0 = __log2f(t0), L1 = __log2f(t1),
          L2 = __log2f(t2), L3 = __log2f(t3);

    // q(L) = p(L + 2.5/ln2), p = trimmed Giles central * 1.1*sqrt2
    const float K4 = 7.84913e-05f, K3 = 1.781908e-03f, K2 = 1.0031874e-02f,
                K1 = -2.4839395e-01f, K0 = 1.3795727e+00f;
    float p0 = fmaf(K4, L0, K3), p1 = fmaf(K4, L1, K3),
          p2 = fmaf(K4, L2, K3), p3 = fmaf(K4, L3, K3);
    p0 = fmaf(p0, L0, K2); p1 = fmaf(p1, L1, K2);
    p2 = fmaf(p2, L2, K2); p3 = fmaf(p3, L3, K2);
    p0 = fmaf(p0, L0, K1); p1 = fmaf(p1, L1, K1);
    p2 = fmaf(p2, L2, K1); p3 = fmaf(p3, L3, K1);
    p0 = fmaf(p0, L0, K0); p1 = fmaf(p1, L1, K0);
    p2 = fmaf(p2, L2, K0); p3 = fmaf(p3, L3, K0);

    if (L0 <= -7.2134752f) p0 = noise_tail(L0);
    if (L1 <= -7.2134752f) p1 = noise_tail(L1);
    if (L2 <= -7.2134752f) p2 = noise_tail(L2);
    if (L3 <= -7.2134752f) p3 = noise_tail(L3);

    float4 n;
    n.x = p0 * v0; n.y = p1 * v1; n.z = p2 * v2; n.w = p3 * v3;
    return n;
}

__device__ __forceinline__ float ssq4(float4 a) {
    return fmaf(a.x, a.x, fmaf(a.y, a.y, fmaf(a.z, a.z, a.w * a.w)));
}

// One WAVE per row (64 lanes x 16 elems); 4 rows per 256-thread block.
// TRUE LOOPS (#pragma unroll 1): hot body shrinks ~4x so all resident waves
// share hot I$ lines instead of streaming 12 KB of straight-line code.
// Pass A: ssq + reduce. Pass B: re-read group (L1-hot), noise, fuse, store.
__global__ void __launch_bounds__(256)
gaussian_dp_kernel(const float* __restrict__ in, float* __restrict__ out) {
    const int wid  = threadIdx.x >> 6;
    const int lane = threadIdx.x & 63;
    const int r    = (blockIdx.x << 2) + wid;   // 0..16383

    const float4* inR  = reinterpret_cast<const float4*>(in  + (size_t)r * COLS) + lane;
    float4*       outR = reinterpret_cast<float4*>(out + (size_t)r * COLS) + lane;

    float ssq = 0.0f;
    #pragma unroll 1
    for (int g = 0; g < 4; ++g) {
        float4 a = inR[g << 6];
        ssq += ssq4(a);
    }

    #pragma unroll
    for (int off = 32; off > 0; off >>= 1) {
        ssq += __shfl_xor(ssq, off, 64);
    }

    const float scale = 1.0f / fmaxf(__builtin_amdgcn_sqrtf(ssq), 1.0f);

    const uint32_t base = ((uint32_t)r << 10) + ((uint32_t)lane << 2);

    #pragma unroll 1
    for (int g = 0; g < 4; ++g) {
        float4 a = inR[g << 6];                       // L1-hot re-read
        float4 n = noise4(base + ((uint32_t)g << 8));
        float4 o;
        o.x = fmaf(a.x, scale, n.x);
        o.y = fmaf(a.y, scale, n.y);
        o.z = fmaf(a.z, scale, n.z);
        o.w = fmaf(a.w, scale, n.w);
        outR[g << 6] = o;
    }
}

extern "C" void kernel_launch(void* const* d_in, const int* in_sizes, int n_in,
                              void* d_out, int out_size, void* d_ws, size_t ws_size,
                              hipStream_t stream) {
    const float* in = (const float*)d_in[0];
    float* out = (float*)d_out;
    gaussian_dp_kernel<<<ROWS / 4, 256, 0, stream>>>(in, out);
}

// Round 9
// 40.538 us; speedup vs baseline: 1.3065x; 1.3065x over previous
//
#include <hip/hip_runtime.h>
#include <cstdint>
#include <cstddef>

#define ROWS 16384
#define COLS 1024

// rotl via single v_alignbit_b32: alignbit(x,x,32-r) = (x>>(32-r))|(x<<r)
__device__ __forceinline__ uint32_t rotl32(uint32_t x, int r) {
    return __builtin_amdgcn_alignbit(x, x, 32 - r);
}

// Four Threefry-2x32 states in lockstep.
struct TF4 { uint32_t a0,a1,b0,b1,c0,c1,d0,d1; };

__device__ __forceinline__ void tf_round4(TF4& s, int r) {
    s.a0 += s.a1; s.b0 += s.b1; s.c0 += s.c1; s.d0 += s.d1;
    s.a1 = rotl32(s.a1, r) ^ s.a0;
    s.b1 = rotl32(s.b1, r) ^ s.b0;
    s.c1 = rotl32(s.c1, r) ^ s.c0;
    s.d1 = rotl32(s.d1, r) ^ s.d0;
}

// Round with the preceding x0-injection folded in: x0 = x0 + x1 + k
// (associative mod 2^32; single v_add3_u32, k from SGPR or inline const).
__device__ __forceinline__ void tf_round4_k(TF4& s, int r, uint32_t k) {
    s.a0 = s.a0 + s.a1 + k; s.b0 = s.b0 + s.b1 + k;
    s.c0 = s.c0 + s.c1 + k; s.d0 = s.d0 + s.d1 + k;
    s.a1 = rotl32(s.a1, r) ^ s.a0;
    s.b1 = rotl32(s.b1, r) ^ s.b0;
    s.c1 = rotl32(s.c1, r) ^ s.c0;
    s.d1 = rotl32(s.d1, r) ^ s.d0;
}

__device__ __forceinline__ void inj4_x1(TF4& s, uint32_t k1) {  // x1 += k only
    s.a1 += k1; s.b1 += k1; s.c1 += k1; s.d1 += k1;
}

// Threefry-2x32-20, key (0,42), counters (0, i..i+3), bits = o0 ^ o1.
// x0-side key injections are folded into the next round via v_add3.
__device__ __forceinline__ uint4 threefry_bits4(uint32_t i, uint32_t ks2_s) {
    const uint32_t ks1 = 42u;
    const uint32_t ks2 = 0x1BD11BF0u;   // 0x1BD11BDA ^ 0 ^ 42

    TF4 s;
    s.a1 = i + 42u;  s.a0 = s.a1;       // x0 = 0 + x1 after round-1 add
    s.b1 = i + 43u;  s.b0 = s.b1;
    s.c1 = i + 44u;  s.c0 = s.c1;
    s.d1 = i + 45u;  s.d0 = s.d1;
    s.a1 = rotl32(s.a1, 13) ^ s.a0;     // round-1 tail
    s.b1 = rotl32(s.b1, 13) ^ s.b0;
    s.c1 = rotl32(s.c1, 13) ^ s.c0;
    s.d1 = rotl32(s.d1, 13) ^ s.d0;
    tf_round4(s, 15); tf_round4(s, 26); tf_round4(s, 6);
    inj4_x1(s, ks2 + 1u);               // x0+=ks1 folded into next round
    tf_round4_k(s, 17, ks1);            // 42 = inline const
    tf_round4(s, 29); tf_round4(s, 16); tf_round4(s, 24);
    inj4_x1(s, 2u);                     // x0+=ks2 folded into next round
    tf_round4_k(s, 13, ks2_s);          // SGPR
    tf_round4(s, 15); tf_round4(s, 26); tf_round4(s, 6);
    inj4_x1(s, ks1 + 3u);               // x0 += 0 here (ks0==0)
    tf_round4(s, 17); tf_round4(s, 29); tf_round4(s, 16); tf_round4(s, 24);
    inj4_x1(s, ks2 + 4u);               // x0+=ks1 folded into next round
    tf_round4_k(s, 13, ks1);            // 42 = inline const
    tf_round4(s, 15); tf_round4(s, 26); tf_round4(s, 6);
    // final injection: x0 += ks2 (literal VOP2 add), x1 += 5, then xor
    s.a0 += ks2; s.b0 += ks2; s.c0 += ks2; s.d0 += ks2;
    s.a1 += 5u;  s.b1 += 5u;  s.c1 += 5u;  s.d1 += 5u;

    return make_uint4(s.a0 ^ s.a1, s.b0 ^ s.b1, s.c0 ^ s.c1, s.d0 ^ s.d1);
}

// Rare tail (L <= -7.2134752 i.e. w >= 5, ~0.33%/lane): Giles upper branch,
// coefficients pre-scaled by 1.1*sqrt(2). Takes L = log2(1 - v^2).
__device__ __noinline__ float noise_tail(float L) {
    float w = -0.69314718f * L;
    float s = __builtin_amdgcn_sqrtf(w) - 3.0f;
    float q = -3.1146030e-04f;
    q = fmaf(q, s, 1.5704224e-04f);
    q = fmaf(q, s, 2.0990855e-03f);
    q = fmaf(q, s, -5.7144932e-03f);
    q = fmaf(q, s, 8.9285939e-03f);
    q = fmaf(q, s, -1.1857797e-02f);
    q = fmaf(q, s, 1.4683435e-02f);
    q = fmaf(q, s, 1.5582439e+00f);
    q = fmaf(q, s, 4.4070777e+00f);
    return q;
}

// 4 elements, stage-interleaved. v = fma(cvt(bits>>9), 2^-22, minval) is
// bit-identical to JAX's bitcast path. Central poly: Giles coeffs pre-scaled
// by 1.1*sqrt2, re-centered in L = log2(1-v^2); high-order terms dropped
// (adds <=2.4e-3 vs 0.12 budget; continuity at branch point verified).
__device__ __forceinline__ float4 noise4(uint32_t idx0, uint32_t ks2_s) {
    uint4 b = threefry_bits4(idx0, ks2_s);

    float f0 = (float)(b.x >> 9);
    float f1 = (float)(b.y >> 9);
    float f2 = (float)(b.z >> 9);
    float f3 = (float)(b.w >> 9);

    const float S = 2.3841858e-07f;      // 2^-22
    const float M = -0.99999994f;
    float v0 = fmaf(f0, S, M), v1 = fmaf(f1, S, M),
          v2 = fmaf(f2, S, M), v3 = fmaf(f3, S, M);

    float t0 = fmaf(-v0, v0, 1.0f), t1 = fmaf(-v1, v1, 1.0f),
          t2 = fmaf(-v2, v2, 1.0f), t3 = fmaf(-v3, v3, 1.0f);

    float L0 = __log2f(t0), L1 = __log2f(t1),
          L2 = __log2f(t2), L3 = __log2f(t3);

    const float K4 = 7.84913e-05f, K3 = 1.781908e-03f, K2 = 1.0031874e-02f,
                K1 = -2.4839395e-01f, K0 = 1.3795727e+00f;
    float p0 = fmaf(K4, L0, K3), p1 = fmaf(K4, L1, K3),
          p2 = fmaf(K4, L2, K3), p3 = fmaf(K4, L3, K3);
    p0 = fmaf(p0, L0, K2); p1 = fmaf(p1, L1, K2);
    p2 = fmaf(p2, L2, K2); p3 = fmaf(p3, L3, K2);
    p0 = fmaf(p0, L0, K1); p1 = fmaf(p1, L1, K1);
    p2 = fmaf(p2, L2, K1); p3 = fmaf(p3, L3, K1);
    p0 = fmaf(p0, L0, K0); p1 = fmaf(p1, L1, K0);
    p2 = fmaf(p2, L2, K0); p3 = fmaf(p3, L3, K0);

    if (L0 <= -7.2134752f) p0 = noise_tail(L0);
    if (L1 <= -7.2134752f) p1 = noise_tail(L1);
    if (L2 <= -7.2134752f) p2 = noise_tail(L2);
    if (L3 <= -7.2134752f) p3 = noise_tail(L3);

    float4 n;
    n.x = p0 * v0; n.y = p1 * v1; n.z = p2 * v2; n.w = p3 * v3;
    return n;
}

__device__ __forceinline__ float ssq4(float4 a) {
    return fmaf(a.x, a.x, fmaf(a.y, a.y, fmaf(a.z, a.z, a.w * a.w)));
}

// One WAVE per row (64 lanes x 16 elems); 4 rows per 256-thread block.
// Straight-line body (R7 structure — looped variant measured 30% slower).
__global__ void __launch_bounds__(256)
gaussian_dp_kernel(const float* __restrict__ in, float* __restrict__ out) {
    const int wid  = threadIdx.x >> 6;
    const int lane = threadIdx.x & 63;
    const int r    = (blockIdx.x << 2) + wid;   // 0..16383

    uint32_t ks2_s = 0x1BD11BF0u;
    asm("" : "+s"(ks2_s));                      // pin for v_add3 (no VOP3 literal)

    const float4* inR = reinterpret_cast<const float4*>(in + (size_t)r * COLS);
    float4 a0 = inR[lane];
    float4 a1 = inR[lane + 64];
    float4 a2 = inR[lane + 128];
    float4 a3 = inR[lane + 192];

    const uint32_t base = ((uint32_t)r << 10) + ((uint32_t)lane << 2);

    float4 n0 = noise4(base,        ks2_s);
    float4 n1 = noise4(base + 256u, ks2_s);
    float4 n2 = noise4(base + 512u, ks2_s);
    float4 n3 = noise4(base + 768u, ks2_s);

    float ssq = (ssq4(a0) + ssq4(a1)) + (ssq4(a2) + ssq4(a3));

    #pragma unroll
    for (int off = 32; off > 0; off >>= 1) {
        ssq += __shfl_xor(ssq, off, 64);
    }

    const float scale = 1.0f / fmaxf(__builtin_amdgcn_sqrtf(ssq), 1.0f);

    float4* outR = reinterpret_cast<float4*>(out + (size_t)r * COLS);

    float4 o;
    o.x = fmaf(a0.x, scale, n0.x); o.y = fmaf(a0.y, scale, n0.y);
    o.z = fmaf(a0.z, scale, n0.z); o.w = fmaf(a0.w, scale, n0.w);
    outR[lane] = o;

    o.x = fmaf(a1.x, scale, n1.x); o.y = fmaf(a1.y, scale, n1.y);
    o.z = fmaf(a1.z, scale, n1.z); o.w = fmaf(a1.w, scale, n1.w);
    outR[lane + 64] = o;

    o.x = fmaf(a2.x, scale, n2.x); o.y = fmaf(a2.y, scale, n2.y);
    o.z = fmaf(a2.z, scale, n2.z); o.w = fmaf(a2.w, scale, n2.w);
    outR[lane + 128] = o;

    o.x = fmaf(a3.x, scale, n3.x); o.y = fmaf(a3.y, scale, n3.y);
    o.z = fmaf(a3.z, scale, n3.z); o.w = fmaf(a3.w, scale, n3.w);
    outR[lane + 192] = o;
}

extern "C" void kernel_launch(void* const* d_in, const int* in_sizes, int n_in,
                              void* d_out, int out_size, void* d_ws, size_t ws_size,
                              hipStream_t stream) {
    const float* in = (const float*)d_in[0];
    float* out = (float*)d_out;
    gaussian_dp_kernel<<<ROWS / 4, 256, 0, stream>>>(in, out);
}